// Round 2
// baseline (1508.525 us; speedup 1.0000x reference)
//
#include <hip/hip_runtime.h>
#include <hip/hip_bf16.h>
#include <math.h>

typedef __hip_bfloat16 bf16;

#define DIMD 128
#define BB 8
#define LL 128
#define TT 512

// Runtime-dtype load of external inputs: bf==1 -> bf16, else f32.
__device__ __forceinline__ float LD(const void* p, long i, int bf) {
    if (bf) return __bfloat162float(((const bf16*)p)[i]);
    return ((const float*)p)[i];
}

// Detect external dtype from emb_W bit patterns + zero the accumulators.
// bf16 data: bits[15:8] of each dword = sign+exponent byte of an N(0,0.05)
// value -> (b & 0x7f) in [0x38,0x3f] nearly always. f32 data: uniform mantissa
// byte -> ~6% hit rate.
__global__ void init_ws(const unsigned int* __restrict__ embw_raw,
                        float* __restrict__ accum, int* __restrict__ flagp) {
    int t = threadIdx.x;
    if (t < 32) accum[t] = 0.0f;
    if (t == 0) {
        int cnt = 0;
        for (int k = 0; k < 256; ++k) {
            unsigned int b = (embw_raw[k] >> 8) & 0xffu;
            unsigned int e = b & 0x7fu;
            if (e >= 0x38u && e <= 0x3fu) ++cnt;
        }
        *flagp = (cnt > 128) ? 1 : 0;
    }
}

// out[row,d] = sum_k X[row,k] * W[k,d]   (X external dtype, K=54)
__global__ void embed_rows(const void* __restrict__ X, const void* __restrict__ W,
                           float* __restrict__ out, int K, const int* __restrict__ flagp) {
    __shared__ float xrow[DIMD];
    int bf = *flagp;
    int row = blockIdx.x;
    int d = threadIdx.x;
    if (d < K) xrow[d] = LD(X, (long)row * K + d, bf);
    __syncthreads();
    float acc = 0.0f;
    for (int k = 0; k < K; ++k)
        acc = fmaf(xrow[k], LD(W, (long)k * DIMD + d, bf), acc);
    out[(long)row * DIMD + d] = acc;
}

// out[row,d] = sum_k X[row,k] * W[offW + k*128 + d] (+ bias[offB+d])
// X internal f32, K=128. Layer offsets passed in ELEMENTS (dtype-agnostic).
__global__ void gemm_rows_ws(const float* __restrict__ X, const void* __restrict__ W,
                             long offW, const void* __restrict__ bias, long offB,
                             int hasbias, float* __restrict__ out,
                             const int* __restrict__ flagp) {
    __shared__ float xrow[DIMD];
    int bf = *flagp;
    int row = blockIdx.x;
    int d = threadIdx.x;
    xrow[d] = X[(long)row * DIMD + d];
    __syncthreads();
    float acc = hasbias ? LD(bias, offB + d, bf) : 0.0f;
    for (int k = 0; k < DIMD; ++k)
        acc = fmaf(xrow[k], LD(W, offW + (long)k * DIMD + d, bf), acc);
    out[(long)row * DIMD + d] = acc;
}

// One block per (b, j). 256 threads. In-place update of x row j.
__global__ void gat_layer(float* __restrict__ x, const float* __restrict__ h,
                          const float* __restrict__ hA, const void* __restrict__ adj,
                          const void* __restrict__ gW, long offgW,
                          const void* __restrict__ gb, long offgb,
                          int N, const int* __restrict__ flagp) {
    __shared__ float haj[DIMD], hj[DIMD], hp[DIMD];
    __shared__ float att[TT], adjrow[TT];
    __shared__ float red[256];
    int bf = *flagp;
    int j = blockIdx.x, b = blockIdx.y, t = threadIdx.x;
    const float* hB = h + (long)b * N * DIMD;
    const float* hAB = hA + (long)b * N * DIMD;
    if (t < DIMD) {
        haj[t] = hAB[(long)j * DIMD + t];
        hj[t] = hB[(long)j * DIMD + t];
    }
    __syncthreads();
    // e_sym[j,k] = hA_j . h_k + hA_k . h_j ; mask by adj
    long adjbase = ((long)b * N + j) * N;
    for (int k = t; k < N; k += 256) {
        const float* hk = hB + (long)k * DIMD;
        const float* hak = hAB + (long)k * DIMD;
        float s = 0.0f;
        for (int i = 0; i < DIMD; ++i)
            s = fmaf(hk[i], haj[i], fmaf(hak[i], hj[i], s));
        float a = LD(adj, adjbase + k, bf);
        adjrow[k] = a;
        att[k] = (a > 0.0f) ? s : -9e15f;
    }
    __syncthreads();
    // softmax over k (denominator over all k, adj applied after -> matches JAX)
    float lm = -3.4e38f;
    for (int k = t; k < N; k += 256) lm = fmaxf(lm, att[k]);
    red[t] = lm; __syncthreads();
    for (int s = 128; s > 0; s >>= 1) { if (t < s) red[t] = fmaxf(red[t], red[t + s]); __syncthreads(); }
    float m = red[0]; __syncthreads();
    float ls = 0.0f;
    for (int k = t; k < N; k += 256) {
        float v = expf(att[k] - m);   // masked: exp(-9e15 - m) -> 0
        ls += v;
        att[k] = v * adjrow[k];
    }
    red[t] = ls; __syncthreads();
    for (int s = 128; s > 0; s >>= 1) { if (t < s) red[t] += red[t + s]; __syncthreads(); }
    float inv = 1.0f / red[0]; __syncthreads();
    // hp[d] = relu(sum_k att[k] * h[k,d]) ; k split over thread halves
    int d = t & (DIMD - 1);
    int kh = t >> 7;
    float acc = 0.0f;
    for (int k = kh; k < N; k += 2)
        acc = fmaf(att[k], hB[(long)k * DIMD + d], acc);
    red[t] = acc; __syncthreads();
    if (t < DIMD) hp[t] = fmaxf((red[t] + red[t + DIMD]) * inv, 0.0f);
    __syncthreads();
    // coeff = sigmoid(concat(x_j, hp) @ gW + gb); x_j = coeff*x_j + (1-coeff)*hp
    float* xrow = x + ((long)b * N + j) * DIMD;
    float gv;
    if (t < DIMD) gv = xrow[t] * LD(gW, offgW + t, bf);
    else          gv = hp[t - DIMD] * LD(gW, offgW + t, bf);
    red[t] = gv; __syncthreads();
    for (int s = 128; s > 0; s >>= 1) { if (t < s) red[t] += red[t + s]; __syncthreads(); }
    float g = red[0] + LD(gb, offgb, bf);
    float coeff = 1.0f / (1.0f + expf(-g));
    __syncthreads();
    if (t < DIMD) xrow[t] = coeff * xrow[t] + (1.0f - coeff) * hp[t];
}

// One block per (b, l). 256 threads, each strides over t in [0,512).
__global__ void pair_energy(const float* __restrict__ ligdc, const float* __restrict__ tgtdc,
                            const float* __restrict__ ligA, const float* __restrict__ tgtA,
                            const void* __restrict__ dcW2, const void* __restrict__ dcb2,
                            const void* __restrict__ AW2, const void* __restrict__ Ab2,
                            const void* __restrict__ lpos, const void* __restrict__ tpos,
                            const void* __restrict__ lrad, const void* __restrict__ trad,
                            const void* __restrict__ lval, const void* __restrict__ tval,
                            const void* __restrict__ ii, float* __restrict__ accum,
                            const int* __restrict__ flagp) {
    int bf = *flagp;
    int l = blockIdx.x, b = blockIdx.y, t = threadIdx.x;
    __shared__ float sdc[DIMD], sA[DIMD], w2dc[DIMD], w2A[DIMD];
    __shared__ float red[256];
    if (t < DIMD) {
        sdc[t] = ligdc[((long)b * LL + l) * DIMD + t];
        sA[t] = ligA[((long)b * LL + l) * DIMD + t];
        w2dc[t] = LD(dcW2, t, bf);
        w2A[t] = LD(AW2, t, bf);
    }
    __syncthreads();
    float lx = LD(lpos, ((long)b * LL + l) * 3 + 0, bf);
    float ly = LD(lpos, ((long)b * LL + l) * 3 + 1, bf);
    float lz = LD(lpos, ((long)b * LL + l) * 3 + 2, bf);
    float lr = LD(lrad, (long)b * LL + l, bf);
    float lv = LD(lval, (long)b * LL + l, bf);
    float cdcb2 = LD(dcb2, 0, bf), cab2 = LD(Ab2, 0, bf);
    long ii0 = ((long)(b * 3 + 0) * LL + l) * TT;
    long ii1 = ((long)(b * 3 + 1) * LL + l) * TT;
    long ii2 = ((long)(b * 3 + 2) * LL + l) * TT;
    float p0 = 0.0f, p1 = 0.0f, p2 = 0.0f, p3 = 0.0f;
    for (int tt = t; tt < TT; tt += 256) {
        float dx = lx - LD(tpos, ((long)b * TT + tt) * 3 + 0, bf);
        float dy = ly - LD(tpos, ((long)b * TT + tt) * 3 + 1, bf);
        float dz = lz - LD(tpos, ((long)b * TT + tt) * 3 + 2, bf);
        float dm = sqrtf(dx * dx + dy * dy + dz * dz + 1e-10f);
        if (dm < 0.5f) dm = 1e10f;
        const float* td = tgtdc + ((long)b * TT + tt) * DIMD;
        const float* ta = tgtA + ((long)b * TT + tt) * DIMD;
        float adc = 0.0f, aA = 0.0f;
        for (int i = 0; i < DIMD; ++i) {
            adc = fmaf(fmaxf(td[i] + sdc[i], 0.0f), w2dc[i], adc);
            aA  = fmaf(fmaxf(ta[i] + sA[i],  0.0f), w2A[i],  aA);
        }
        float dev = tanhf(adc + cdcb2) * 0.2f;
        float vdws = lr + LD(trad, (long)b * TT + tt, bf) + dev;
        float dm0 = (vdws < 1e-4f) ? 1.0f : vdws;
        float ratio = dm0 / dm;
        float r2 = ratio * ratio, r6 = r2 * r2 * r2, r12 = r6 * r6;
        float en = fminf(r12 - 2.0f * r6, 100.0f) * lv * LD(tval, (long)b * TT + tt, bf);
        float As = 1.0f / (1.0f + expf(-(aA + cab2)));
        As = As * (0.0356f - 0.0178f) + 0.0178f;
        p0 = fmaf(As, en, p0);
        float dd = dm - vdws;
        float ramp = fminf(fmaxf(dd * (1.0f / -0.7f), 0.0f), 1.0f);
        p1 = fmaf(ramp, LD(ii, ii0 + tt, bf), p1);
        p2 = fmaf(ramp, LD(ii, ii1 + tt, bf), p2);
        float ramp2 = fminf(fmaxf(-dd + 1.5f, 0.0f), 1.0f);
        p3 = fmaf(ramp2, LD(ii, ii2 + tt, bf), p3);
    }
    for (int e = 0; e < 4; ++e) {
        float v = (e == 0) ? p0 : (e == 1) ? p1 : (e == 2) ? p2 : p3;
        red[t] = v; __syncthreads();
        for (int s = 128; s > 0; s >>= 1) { if (t < s) red[t] += red[t + s]; __syncthreads(); }
        if (t == 0) atomicAdd(&accum[b * 4 + e], red[0]);
        __syncthreads();
    }
}

__global__ void finalize(const float* __restrict__ accum, const void* __restrict__ hb,
                         const void* __restrict__ mc, const void* __restrict__ hyd,
                         const void* __restrict__ rc, const void* __restrict__ rotor,
                         void* __restrict__ out, const int* __restrict__ flagp) {
    int bf = *flagp;
    int t = threadIdx.x;  // 64 threads, use first 32
    if (t >= 32) return;
    int b = t >> 2, e = t & 3;
    float v = accum[t];
    if (e == 1) { float c = LD(hb, 0, bf);  v = -c * c * v; }
    else if (e == 2) { float c = LD(mc, 0, bf);  v = -c * c * v; }
    else if (e == 3) { float c = LD(hyd, 0, bf); v = -c * c * v; }
    float r = LD(rc, 0, bf);
    float den = 1.0f + r * r * LD(rotor, b, bf);
    float res = v / den;
    if (bf) ((bf16*)out)[t] = __float2bfloat16(res);
    else    ((float*)out)[t] = res;
}

extern "C" void kernel_launch(void* const* d_in, const int* in_sizes, int n_in,
                              void* d_out, int out_size, void* d_ws, size_t ws_size,
                              hipStream_t stream) {
    const void* ligand_h = d_in[0];
    const void* target_h = d_in[1];
    const void* ligand_adj = d_in[2];
    const void* target_adj = d_in[3];
    const void* interaction_indice = d_in[4];
    const void* ligand_pos = d_in[5];
    const void* target_pos = d_in[6];
    const void* rotor = d_in[7];
    const void* ligand_vdw = d_in[8];
    const void* target_vdw = d_in[9];
    const void* ligand_valid = d_in[10];
    const void* target_valid = d_in[11];
    const void* emb_W = d_in[12];
    const void* gat_W = d_in[13];
    const void* gat_Wb = d_in[14];
    const void* gat_A = d_in[15];
    const void* gat_gW = d_in[16];
    const void* gat_gb = d_in[17];
    const void* vdwA_W1 = d_in[18];
    const void* vdwA_b1 = d_in[19];
    const void* vdwA_W2 = d_in[20];
    const void* vdwA_b2 = d_in[21];
    const void* dc_W1 = d_in[22];
    const void* dc_b1 = d_in[23];
    const void* dc_W2 = d_in[24];
    const void* dc_b2 = d_in[25];
    const void* hbond_coeff = d_in[26];
    const void* metal_coeff = d_in[27];
    const void* hydrophobic_coeff = d_in[28];
    const void* rotor_coeff = d_in[29];

    float* ws = (float*)d_ws;
    size_t off = 0;
    float* lig_x = ws + off;  off += (size_t)BB * LL * DIMD;
    float* tgt_x = ws + off;  off += (size_t)BB * TT * DIMD;
    float* h_lig = ws + off;  off += (size_t)BB * LL * DIMD;
    float* h_tgt = ws + off;  off += (size_t)BB * TT * DIMD;
    float* hA_lig = ws + off; off += (size_t)BB * LL * DIMD;
    float* hA_tgt = ws + off; off += (size_t)BB * TT * DIMD;
    float* accum = ws + off;  off += 32;
    int* flagp = (int*)(ws + off); off += 2;
    // pair-MLP projections reuse h/hA buffers (dead after the GAT loop)
    float* ligdc = h_lig;
    float* tgtdc = h_tgt;
    float* ligA = hA_lig;
    float* tgtA = hA_tgt;

    init_ws<<<1, 64, 0, stream>>>((const unsigned int*)emb_W, accum, flagp);

    // embeddings: x = h @ emb_W
    embed_rows<<<BB * LL, DIMD, 0, stream>>>(ligand_h, emb_W, lig_x, 54, flagp);
    embed_rows<<<BB * TT, DIMD, 0, stream>>>(target_h, emb_W, tgt_x, 54, flagp);

    for (int i = 0; i < 3; ++i) {
        long offW = (long)i * DIMD * DIMD;   // element offsets (dtype-agnostic)
        long offWb = (long)i * DIMD;
        long offgW = (long)i * 2 * DIMD;
        long offgb = i;
        gemm_rows_ws<<<BB * LL, DIMD, 0, stream>>>(lig_x, gat_W, offW, gat_Wb, offWb, 1, h_lig, flagp);
        gemm_rows_ws<<<BB * LL, DIMD, 0, stream>>>(h_lig, gat_A, offW, nullptr, 0, 0, hA_lig, flagp);
        gat_layer<<<dim3(LL, BB), 256, 0, stream>>>(lig_x, h_lig, hA_lig, ligand_adj,
                                                    gat_gW, offgW, gat_gb, offgb, LL, flagp);
        gemm_rows_ws<<<BB * TT, DIMD, 0, stream>>>(tgt_x, gat_W, offW, gat_Wb, offWb, 1, h_tgt, flagp);
        gemm_rows_ws<<<BB * TT, DIMD, 0, stream>>>(h_tgt, gat_A, offW, nullptr, 0, 0, hA_tgt, flagp);
        gat_layer<<<dim3(TT, BB), 256, 0, stream>>>(tgt_x, h_tgt, hA_tgt, target_adj,
                                                    gat_gW, offgW, gat_gb, offgb, TT, flagp);
    }

    // pair-MLP projections (split W1 == concat math; b1 folded into ligand side)
    gemm_rows_ws<<<BB * LL, DIMD, 0, stream>>>(lig_x, dc_W1, 0, dc_b1, 0, 1, ligdc, flagp);
    gemm_rows_ws<<<BB * TT, DIMD, 0, stream>>>(tgt_x, dc_W1, (long)DIMD * DIMD, nullptr, 0, 0, tgtdc, flagp);
    gemm_rows_ws<<<BB * LL, DIMD, 0, stream>>>(lig_x, vdwA_W1, 0, vdwA_b1, 0, 1, ligA, flagp);
    gemm_rows_ws<<<BB * TT, DIMD, 0, stream>>>(tgt_x, vdwA_W1, (long)DIMD * DIMD, nullptr, 0, 0, tgtA, flagp);

    pair_energy<<<dim3(LL, BB), 256, 0, stream>>>(
        ligdc, tgtdc, ligA, tgtA, dc_W2, dc_b2, vdwA_W2, vdwA_b2,
        ligand_pos, target_pos, ligand_vdw, target_vdw,
        ligand_valid, target_valid, interaction_indice, accum, flagp);

    finalize<<<1, 64, 0, stream>>>(accum, hbond_coeff, metal_coeff,
                                   hydrophobic_coeff, rotor_coeff, rotor, d_out, flagp);
}